// Round 1
// 752.429 us; speedup vs baseline: 1.1306x; 1.1306x over previous
//
#include <hip/hip_runtime.h>
#include <math.h>

#define HW   3136
#define NC   200
#define NB   32
#define SS   56
#define OS   224
#define KS   33
#define GPAD 16

typedef __attribute__((ext_vector_type(8))) short          short8;
typedef __attribute__((ext_vector_type(4))) float          f32x4;
typedef __attribute__((ext_vector_type(4))) unsigned short ush4;

__device__ __forceinline__ unsigned short f2bf(float x) {
    unsigned int u = __builtin_bit_cast(unsigned int, x);
    u += 0x7FFFu + ((u >> 16) & 1u);          // RNE (inputs finite)
    return (unsigned short)(u >> 16);
}
__device__ __forceinline__ float bf2f(unsigned short h) {
    unsigned int u = ((unsigned int)h) << 16;
    return __builtin_bit_cast(float, u);
}

// async global->LDS, 16B per lane. LDS dest is wave-uniform base + lane*16.
__device__ __forceinline__ void gload16(const void* g, void* l) {
    __builtin_amdgcn_global_load_lds(
        (const __attribute__((address_space(1))) void*)g,
        (__attribute__((address_space(3))) void*)l, 16, 0, 0);
}

// ---------------------------------------------------------------------------
// K0: coalesced delta transpose. emb[b][c][n]-mean[c][n] -> bf16, laid out
// per pixel as 7 K-chunks [kt][b 0..31][c-in-chunk 0..31] (zero-padded c>=200)
// so k_mahal2 can global_load_lds it linearly and read B-fragments/epilogue
// directly. Grid: 196 n-tiles x 4 b-quarters = 784 blocks.
// ---------------------------------------------------------------------------
__global__ __launch_bounds__(256)
void k_delta(const float* __restrict__ emb,
             const float* __restrict__ mean,
             unsigned short* __restrict__ dg) {
    const int tile = blockIdx.x >> 2;
    const int bq   = blockIdx.x & 3;          // b-quarter: b = bq*8 .. bq*8+7
    const int n0   = tile * 16;
    const int t    = threadIdx.x;

    __shared__ float          mm[32 * 20];    // mean chunk [cl][nl], pad 20
    __shared__ unsigned short tr[256 * 20];   // [b_lo*32+cl][nl], pad 20

    unsigned int* dgU = (unsigned int*)dg;

    for (int kt = 0; kt < 7; kt++) {
        const int c0 = kt * 32;
        // mean chunk: 32 c x 16 n
        if (t < 128) {
            int cl = t >> 2, nl4 = (t & 3) * 4;
            int c = c0 + cl;
            float4 v = {0.f, 0.f, 0.f, 0.f};
            if (c < NC) v = *(const float4*)&mean[(size_t)c * HW + n0 + nl4];
            *(float4*)&mm[cl * 20 + nl4] = v;
        }
        __syncthreads();
        // stage: 256 rows (8 b x 32 cl) x 16 n, 64B-granule coalesced reads
#pragma unroll
        for (int j = 0; j < 4; j++) {
            int row = (t >> 2) + 64 * j;      // 0..255
            int nl4 = (t & 3) * 4;
            int b   = bq * 8 + (row >> 5);
            int cl  = row & 31;
            int c   = c0 + cl;
            ush4 wv = {0, 0, 0, 0};
            if (c < NC) {
                float4 e = *(const float4*)&emb[((size_t)(b * NC + c)) * HW + n0 + nl4];
                float4 m = *(const float4*)&mm[cl * 20 + nl4];
                wv[0] = f2bf(e.x - m.x); wv[1] = f2bf(e.y - m.y);
                wv[2] = f2bf(e.z - m.z); wv[3] = f2bf(e.w - m.w);
            }
            *(ush4*)&tr[row * 20 + nl4] = wv;
        }
        __syncthreads();
        // emit: fully coalesced packed uint writes
#pragma unroll
        for (int j = 0; j < 8; j++) {
            int idx = t + 256 * j;            // 0..2047
            int nl  = idx >> 7, rem = idx & 127;
            int bl  = rem >> 4, cu = rem & 15;
            int cb  = bl * 32 + 2 * cu;
            unsigned int lo = tr[cb * 20 + nl];
            unsigned int hi = tr[(cb + 1) * 20 + nl];
            dgU[((size_t)(n0 + nl) * 7 + kt) * 512 +
                (size_t)(bq * 8 + bl) * 16 + cu] = lo | (hi << 16);
        }
        __syncthreads();
    }
}

// ---------------------------------------------------------------------------
// K1: per-pixel Mahalanobis, streaming form.
// R[i][b] = sum_k M[i][k] * delta[b][k]  (M rows feed the A-fragment, both
// fragments read as [own-row=col][8k]); q[b] = sum_i R[i][b]*delta[b][i].
// M streams f32 via global_load_lds into a double-buffered 16-row slab,
// one barrier per tile; delta sits in LDS (bf16, chunked) + register B-frags.
// LDS 40KB -> 4 blocks/CU.
// ---------------------------------------------------------------------------
__global__ __launch_bounds__(256, 4)
void k_mahal2(const unsigned short* __restrict__ dg,
              const float* __restrict__ icov,
              float* __restrict__ score) {
    const int bid = blockIdx.x;
    const int n = (bid & 7) * 392 + (bid >> 3);   // XCD-contiguous pixel index
    const int t = threadIdx.x;

    __shared__ unsigned short dd[7 * 1024];       // bf16 delta, [kt][b][c&31]
    __shared__ float slab[2][16 * NC];            // f32 M rows, dbuf
    __shared__ float qs[NB];

    const float* Mn   = icov + (size_t)n * (NC * NC);
    const char*  dsrc = (const char*)(dg + (size_t)n * 7168);

    // issue delta (896 x16B) + M tile 0 (800 x16B), both async to LDS
    {
        char* lb = (char*)dd;
#pragma unroll
        for (int i = 0; i < 4; i++) {
            int idx = i * 256 + t;
            if (idx < 896)
                gload16(dsrc + (size_t)idx * 16, lb + (i * 256 + (t & 192)) * 16);
        }
        const char* ms = (const char*)Mn;
        char* sb = (char*)&slab[0][0];
#pragma unroll
        for (int i = 0; i < 4; i++) {
            int idx = i * 256 + t;
            if (idx < 800)
                gload16(ms + (size_t)idx * 16, sb + (i * 256 + (t & 192)) * 16);
        }
    }
    if (t < NB) qs[t] = 0.f;
    __syncthreads();                              // drains dd + tile0

    const int lane = t & 63;
    const int w    = t >> 6;
    const int col  = lane & 15;
    const int quad = lane >> 4;
    const int bt   = w & 1;                       // b-tile 0/1
    const int kg   = w >> 1;                      // k-group: kt = kg + 2q
    const int nk   = kg ? 3 : 4;
    const int ddb  = (bt * 16 + col) * 32;

    // B fragments (delta rows) live in registers for the whole kernel
    short8 bF[4];
#pragma unroll
    for (int q = 0; q < 4; q++) {
        if (q < nk) {
            int kt = kg + 2 * q;
            bF[q] = *(const short8*)&dd[kt * 1024 + ddb + quad * 8];
        }
    }

    const int abase = col * NC + quad * 8;
    float qacc = 0.f;

    for (int it = 0; it < 13; it++) {
        // issue next M tile; flies across this tile's compute, drained at the
        // end-of-iteration barrier (compiler emits vmcnt(0) before s_barrier)
        if (it < 12) {
            const int nf4 = (it == 11) ? 400 : 800;   // last tile: 8 real rows
            const char* ms = (const char*)(Mn + (size_t)(it + 1) * 16 * NC);
            char* sb = (char*)&slab[(it + 1) & 1][0];
#pragma unroll
            for (int i = 0; i < 4; i++) {
                int idx = i * 256 + t;
                if (idx < nf4)
                    gload16(ms + (size_t)idx * 16, sb + (i * 256 + (t & 192)) * 16);
            }
        }
        // compute tile it: A-frag = M rows (f32->bf16 at read), 3-4 MFMA
        const float* sl = &slab[it & 1][0];
        f32x4 acc = {0.f, 0.f, 0.f, 0.f};
#pragma unroll
        for (int q = 0; q < 4; q++) {
            if (q < nk) {
                int kt = kg + 2 * q;
                const f32x4* ap = (const f32x4*)&sl[abase + kt * 32];
                f32x4 lo = ap[0], hi = ap[1];
                short8 aF;
                aF[0] = f2bf(lo[0]); aF[1] = f2bf(lo[1]);
                aF[2] = f2bf(lo[2]); aF[3] = f2bf(lo[3]);
                aF[4] = f2bf(hi[0]); aF[5] = f2bf(hi[1]);
                aF[6] = f2bf(hi[2]); aF[7] = f2bf(hi[3]);
                acc = __builtin_amdgcn_mfma_f32_16x16x32_bf16(aF, bF[q], acc, 0, 0, 0);
            }
        }
        // fold: q-partial = sum_r R[i0+r][b]*delta[b][i0+r]; i pads >=200 hit
        // dd zeros, so stale slab rows on the last tile contribute exactly 0.
        {
            int off = (it >> 1) * 1024 + ddb + (it & 1) * 16 + quad * 4;
            ush4 dv = *(const ush4*)&dd[off];
            float v = acc[0] * bf2f(dv[0]) + acc[1] * bf2f(dv[1]) +
                      acc[2] * bf2f(dv[2]) + acc[3] * bf2f(dv[3]);
            v += __shfl_xor(v, 16);
            v += __shfl_xor(v, 32);
            qacc += v;
        }
        __syncthreads();
    }

    if (quad == 0) atomicAdd(&qs[bt * 16 + col], qacc);
    __syncthreads();
    if (t < NB) {
        float q = qs[t];
        score[(size_t)t * HW + n] = sqrtf(q > 0.f ? q : 0.f);
    }
}

// ---------------------------------------------------------------------------
// K2: bilinear 56 -> 224 (half-pixel centers == clamp at edges)
// ---------------------------------------------------------------------------
__global__ void k_upsample(const float* __restrict__ score,
                           float* __restrict__ up) {
    int idx = blockIdx.x * 256 + threadIdx.x;
    if (idx >= NB * OS * OS) return;
    int x = idx % OS;
    int y = (idx / OS) % OS;
    int b = idx / (OS * OS);

    float sy = 0.25f * y - 0.375f;
    float sx = 0.25f * x - 0.375f;
    int y0 = (int)floorf(sy); float fy = sy - (float)y0;
    int x0 = (int)floorf(sx); float fx = sx - (float)x0;
    int y0c = min(max(y0, 0), SS - 1), y1c = min(max(y0 + 1, 0), SS - 1);
    int x0c = min(max(x0, 0), SS - 1), x1c = min(max(x0 + 1, 0), SS - 1);

    const float* sb = score + (size_t)b * HW;
    float v00 = sb[y0c * SS + x0c];
    float v01 = sb[y0c * SS + x1c];
    float v10 = sb[y1c * SS + x0c];
    float v11 = sb[y1c * SS + x1c];
    up[idx] = (1.f - fy) * ((1.f - fx) * v00 + fx * v01) +
              fy * ((1.f - fx) * v10 + fx * v11);
}

// ---------------------------------------------------------------------------
// K3: Gaussian weights (reference numerics: exp(-x^2/32), normalized)
// ---------------------------------------------------------------------------
__global__ void k_gauss_init(float* __restrict__ g) {
    if (threadIdx.x == 0) {
        float e[KS];
        float sum = 0.f;
        for (int i = 0; i < KS; i++) {
            float x = (float)i - 16.0f;
            e[i] = expf(-(x * x) / 32.0f);
            sum += e[i];
        }
        for (int i = 0; i < KS; i++) g[i] = e[i] / sum;
    }
}

__device__ __forceinline__ int reflect224(int i) {
    if (i < 0) return -i;
    if (i > OS - 1) return 2 * (OS - 1) - i;
    return i;
}

__global__ void k_hblur(const float* __restrict__ up,
                        const float* __restrict__ g,
                        float* __restrict__ tmp) {
    int idx = blockIdx.x * 256 + threadIdx.x;
    if (idx >= NB * OS * OS) return;
    int x = idx % OS;
    int row = idx / OS;
    const float* src = up + (size_t)row * OS;
    float acc = 0.f;
#pragma unroll
    for (int t = -GPAD; t <= GPAD; t++) {
        acc += g[t + GPAD] * src[reflect224(x + t)];
    }
    tmp[idx] = acc;
}

__global__ void k_vblur(const float* __restrict__ tmp,
                        const float* __restrict__ g,
                        float* __restrict__ out) {
    int idx = blockIdx.x * 256 + threadIdx.x;
    if (idx >= NB * OS * OS) return;
    int x = idx % OS;
    int y = (idx / OS) % OS;
    int b = idx / (OS * OS);
    const float* src = tmp + (size_t)b * OS * OS;
    float acc = 0.f;
#pragma unroll
    for (int t = -GPAD; t <= GPAD; t++) {
        acc += g[t + GPAD] * src[(size_t)reflect224(y + t) * OS + x];
    }
    out[idx] = acc;
}

// ---------------------------------------------------------------------------
extern "C" void kernel_launch(void* const* d_in, const int* in_sizes, int n_in,
                              void* d_out, int out_size, void* d_ws, size_t ws_size,
                              hipStream_t stream) {
    const float* emb  = (const float*)d_in[0];   // [32,200,56,56]
    const float* mean = (const float*)d_in[1];   // [200,3136]
    const float* icov = (const float*)d_in[2];   // [3136,200,200]
    float* out = (float*)d_out;                  // [32,1,224,224]

    char* ws = (char*)d_ws;
    float* g     = (float*)ws;                            // 33 floats
    float* score = (float*)(ws + 256);                    // 32*3136 floats
    float* tmp   = (float*)(ws + 256 + 401408);           // 32*224*224 floats
    unsigned short* dg = (unsigned short*)(ws + 6824192); // 3136*7168 bf16 (~45MB)

    const int up_blocks = (NB * OS * OS) / 256;           // 6272

    k_gauss_init<<<1, 64, 0, stream>>>(g);
    k_delta<<<784, 256, 0, stream>>>(emb, mean, dg);
    k_mahal2<<<HW, 256, 0, stream>>>(dg, icov, score);
    k_upsample<<<up_blocks, 256, 0, stream>>>(score, out);
    k_hblur<<<up_blocks, 256, 0, stream>>>(out, g, tmp);
    k_vblur<<<up_blocks, 256, 0, stream>>>(tmp, g, out);
}

// Round 2
// 720.084 us; speedup vs baseline: 1.1814x; 1.0449x over previous
//
#include <hip/hip_runtime.h>
#include <math.h>

#define HW   3136
#define NC   200
#define NB   32
#define SS   56
#define OS   224
#define KS   33
#define GPAD 16

typedef __attribute__((ext_vector_type(8))) short          short8;
typedef __attribute__((ext_vector_type(4))) float          f32x4;
typedef __attribute__((ext_vector_type(4))) unsigned short ush4;

__device__ __forceinline__ unsigned short f2bf(float x) {
    unsigned int u = __builtin_bit_cast(unsigned int, x);
    u += 0x7FFFu + ((u >> 16) & 1u);          // RNE (inputs finite)
    return (unsigned short)(u >> 16);
}
__device__ __forceinline__ float bf2f(unsigned short h) {
    unsigned int u = ((unsigned int)h) << 16;
    return __builtin_bit_cast(float, u);
}

// async global->LDS, 16B per lane. LDS dest is wave-uniform base + lane*16.
__device__ __forceinline__ void gload16(const void* g, void* l) {
    __builtin_amdgcn_global_load_lds(
        (const __attribute__((address_space(1))) void*)g,
        (__attribute__((address_space(3))) void*)l, 16, 0, 0);
}

// ---------------------------------------------------------------------------
// K0: coalesced delta transpose. emb[b][c][n]-mean[c][n] -> bf16, laid out
// per pixel as 7 K-chunks [kt][b 0..31][c-in-chunk 0..31] (zero-padded c>=200)
// so k_mahal2 can global_load_lds it linearly and read B-fragments/epilogue
// directly. Grid: 196 n-tiles x 4 b-quarters = 784 blocks.
// ---------------------------------------------------------------------------
__global__ __launch_bounds__(256)
void k_delta(const float* __restrict__ emb,
             const float* __restrict__ mean,
             unsigned short* __restrict__ dg) {
    const int tile = blockIdx.x >> 2;
    const int bq   = blockIdx.x & 3;          // b-quarter: b = bq*8 .. bq*8+7
    const int n0   = tile * 16;
    const int t    = threadIdx.x;

    __shared__ float          mm[32 * 20];    // mean chunk [cl][nl], pad 20
    __shared__ unsigned short tr[256 * 20];   // [b_lo*32+cl][nl], pad 20

    unsigned int* dgU = (unsigned int*)dg;

    for (int kt = 0; kt < 7; kt++) {
        const int c0 = kt * 32;
        // mean chunk: 32 c x 16 n
        if (t < 128) {
            int cl = t >> 2, nl4 = (t & 3) * 4;
            int c = c0 + cl;
            float4 v = {0.f, 0.f, 0.f, 0.f};
            if (c < NC) v = *(const float4*)&mean[(size_t)c * HW + n0 + nl4];
            *(float4*)&mm[cl * 20 + nl4] = v;
        }
        __syncthreads();
        // stage: 256 rows (8 b x 32 cl) x 16 n, 64B-granule coalesced reads
#pragma unroll
        for (int j = 0; j < 4; j++) {
            int row = (t >> 2) + 64 * j;      // 0..255
            int nl4 = (t & 3) * 4;
            int b   = bq * 8 + (row >> 5);
            int cl  = row & 31;
            int c   = c0 + cl;
            ush4 wv = {0, 0, 0, 0};
            if (c < NC) {
                float4 e = *(const float4*)&emb[((size_t)(b * NC + c)) * HW + n0 + nl4];
                float4 m = *(const float4*)&mm[cl * 20 + nl4];
                wv[0] = f2bf(e.x - m.x); wv[1] = f2bf(e.y - m.y);
                wv[2] = f2bf(e.z - m.z); wv[3] = f2bf(e.w - m.w);
            }
            *(ush4*)&tr[row * 20 + nl4] = wv;
        }
        __syncthreads();
        // emit: fully coalesced packed uint writes
#pragma unroll
        for (int j = 0; j < 8; j++) {
            int idx = t + 256 * j;            // 0..2047
            int nl  = idx >> 7, rem = idx & 127;
            int bl  = rem >> 4, cu = rem & 15;
            int cb  = bl * 32 + 2 * cu;
            unsigned int lo = tr[cb * 20 + nl];
            unsigned int hi = tr[(cb + 1) * 20 + nl];
            dgU[((size_t)(n0 + nl) * 7 + kt) * 512 +
                (size_t)(bq * 8 + bl) * 16 + cu] = lo | (hi << 16);
        }
        __syncthreads();
    }
}

// ---------------------------------------------------------------------------
// K1: per-pixel Mahalanobis, symmetric/triangular streaming form.
// M is exactly symmetric, so q = 2*sum_{blockK<blockI} T(I,K) + sum_I T(I,I):
// per row-tile I we stream only k in [0,16(I+1)) (58% of the matrix).
// Block-level factors are per-lane uniform on the A fragment (a lane's 8-wide
// k-range sits entirely in one 16-half): half below diag -> x2 (exact in
// bf16), diag block -> x1, above -> constant-0 fragment (select, no read).
// M rows stream f32 via global_load_lds into a double-buffered padded slab
// (row stride CHp=CH+1 16B-chunks, odd -> conflict-free b128 reads); one
// barrier per tile. Every read region is written by the current tile with
// row/chunk-clamped finite sources, so no LDS-poison NaN can enter the MFMA.
// ---------------------------------------------------------------------------
__global__ __launch_bounds__(256, 4)
void k_mahal2(const unsigned short* __restrict__ dg,
              const float* __restrict__ icov,
              float* __restrict__ score) {
    const int bid = blockIdx.x;
    const int n = (bid & 7) * 392 + (bid >> 3);   // XCD-contiguous pixel index
    const int t = threadIdx.x;

    __shared__ __align__(16) unsigned short dd[7 * 1024]; // bf16 delta [kt][b][c&31]
    __shared__ __align__(16) float slab[2][3200];         // 800 16B-chunks per buf
    __shared__ float qs[NB];

    const float* Mn   = icov + (size_t)n * (NC * NC);
    const char*  dsrc = (const char*)(dg + (size_t)n * 7168);

    // issue delta (896 x16B) + M tile 0 (triangular prefix, 88 chunks), async
    {
        char* lb = (char*)dd;
#pragma unroll
        for (int i = 0; i < 4; i++) {
            int idx = i * 256 + t;
            if (idx < 896)
                gload16(dsrc + (size_t)idx * 16, lb + (i * 256 + (t & 192)) * 16);
        }
        const char* ms = (const char*)Mn;
        char* sb = (char*)&slab[0][0];
        if (t < 88) {                              // nr=16, CH=4, CHp=5, T=88
            int row = t / 5;
            int c   = t - row * 5;
            if (row >= 16) { row = 15; c = 0; }
            if (c >= 4) c = 0;
            gload16(ms + (size_t)row * (NC * 4) + (size_t)c * 16,
                    sb + (t & 192) * 16);
        }
    }
    if (t < NB) qs[t] = 0.f;
    __syncthreads();                              // drains dd + tile0

    const int lane = t & 63;
    const int w    = t >> 6;
    const int col  = lane & 15;
    const int quad = lane >> 4;
    const int bt   = w & 1;                       // b-tile 0/1
    const int kg   = w >> 1;                      // k-group: chunks kg, kg+2, ...
    const int ddb  = (bt * 16 + col) * 32;

    // B fragments (delta rows) live in registers for the whole kernel
    short8 bF[4];
#pragma unroll
    for (int q = 0; q < 4; q++) {
        int kt = kg + 2 * q;
        if (kt < 7)
            bF[q] = *(const short8*)&dd[kt * 1024 + ddb + quad * 8];
    }

    float qacc = 0.f;

#pragma unroll
    for (int it = 0; it < 13; it++) {
        // ---- issue next M tile's triangular prefix (flies across compute,
        //      drained by the end-of-iteration barrier) ----
        if (it < 12) {
            const int tt  = it + 1;
            const int nr  = (tt == 12) ? 8 : 16;
            const int CHn = (4 * (tt + 1) < 50) ? 4 * (tt + 1) : 50;
            const int CHpn = CHn + 1;
            const int T   = nr * CHpn + 8;        // +8 tail pad (clamped srcs)
            const char* ms = (const char*)(Mn + (size_t)tt * 16 * NC);
            char* sb = (char*)&slab[tt & 1][0];
#pragma unroll
            for (int i = 0; i < 4; i++) {
                int idx = i * 256 + t;
                if (idx < T) {
                    int row = idx / CHpn;         // compile-time magic (unrolled)
                    int c   = idx - row * CHpn;
                    if (row >= nr) { row = nr - 1; c = 0; }
                    if (c >= CHn) c = 0;          // stride pad chunk: finite src
                    gload16(ms + (size_t)row * (NC * 4) + (size_t)c * 16,
                            sb + (i * 256 + (t & 192)) * 16);
                }
            }
        }
        // ---- compute tile it ----
        {
            const int CH   = (4 * (it + 1) < 50) ? 4 * (it + 1) : 50;
            const int strd = (CH + 1) * 4;        // floats; odd 16B stride
            const int Cq   = (it + 2) >> 1;       // ceil((it+1)/2) K32-chunks
            const int ig   = 16 * it + col;       // this lane's A-row (M row)
            const float* sl = &slab[it & 1][0];
            f32x4 acc = {0.f, 0.f, 0.f, 0.f};
#pragma unroll
            for (int q = 0; q < 4; q++) {
                const int cq = kg + 2 * q;
                if (cq < Cq) {
                    const int half0 = 32 * cq + (quad >> 1) * 16;
                    float s = 0.f;
                    if (ig < NC) {
                        if (half0 + 16 <= 16 * it) s = 2.f;       // strict lower
                        else if (half0 == 16 * it) s = 1.f;       // diag block
                    }
                    short8 aF = {0, 0, 0, 0, 0, 0, 0, 0};
                    if (s != 0.f) {
                        const f32x4* ap =
                            (const f32x4*)&sl[col * strd + cq * 32 + quad * 8];
                        f32x4 lo = ap[0], hi = ap[1];
                        aF[0] = f2bf(s * lo[0]); aF[1] = f2bf(s * lo[1]);
                        aF[2] = f2bf(s * lo[2]); aF[3] = f2bf(s * lo[3]);
                        aF[4] = f2bf(s * hi[0]); aF[5] = f2bf(s * hi[1]);
                        aF[6] = f2bf(s * hi[2]); aF[7] = f2bf(s * hi[3]);
                    }
                    acc = __builtin_amdgcn_mfma_f32_16x16x32_bf16(aF, bF[q], acc, 0, 0, 0);
                }
            }
            // fold: q-partial = sum_r R[16it+quad*4+r][b] * delta[b][...]
            int off = (it >> 1) * 1024 + ddb + (it & 1) * 16 + quad * 4;
            ush4 dv = *(const ush4*)&dd[off];
            float v = acc[0] * bf2f(dv[0]) + acc[1] * bf2f(dv[1]) +
                      acc[2] * bf2f(dv[2]) + acc[3] * bf2f(dv[3]);
            v += __shfl_xor(v, 16);
            v += __shfl_xor(v, 32);
            qacc += v;
        }
        __syncthreads();
    }

    if (quad == 0) atomicAdd(&qs[bt * 16 + col], qacc);
    __syncthreads();
    if (t < NB) {
        float q = qs[t];
        score[(size_t)t * HW + n] = sqrtf(q > 0.f ? q : 0.f);
    }
}

// ---------------------------------------------------------------------------
// K2: bilinear 56 -> 224 (half-pixel centers == clamp at edges)
// ---------------------------------------------------------------------------
__global__ void k_upsample(const float* __restrict__ score,
                           float* __restrict__ up) {
    int idx = blockIdx.x * 256 + threadIdx.x;
    if (idx >= NB * OS * OS) return;
    int x = idx % OS;
    int y = (idx / OS) % OS;
    int b = idx / (OS * OS);

    float sy = 0.25f * y - 0.375f;
    float sx = 0.25f * x - 0.375f;
    int y0 = (int)floorf(sy); float fy = sy - (float)y0;
    int x0 = (int)floorf(sx); float fx = sx - (float)x0;
    int y0c = min(max(y0, 0), SS - 1), y1c = min(max(y0 + 1, 0), SS - 1);
    int x0c = min(max(x0, 0), SS - 1), x1c = min(max(x0 + 1, 0), SS - 1);

    const float* sb = score + (size_t)b * HW;
    float v00 = sb[y0c * SS + x0c];
    float v01 = sb[y0c * SS + x1c];
    float v10 = sb[y1c * SS + x0c];
    float v11 = sb[y1c * SS + x1c];
    up[idx] = (1.f - fy) * ((1.f - fx) * v00 + fx * v01) +
              fy * ((1.f - fx) * v10 + fx * v11);
}

// ---------------------------------------------------------------------------
// K3: Gaussian weights (reference numerics: exp(-x^2/32), normalized)
// ---------------------------------------------------------------------------
__global__ void k_gauss_init(float* __restrict__ g) {
    if (threadIdx.x == 0) {
        float e[KS];
        float sum = 0.f;
        for (int i = 0; i < KS; i++) {
            float x = (float)i - 16.0f;
            e[i] = expf(-(x * x) / 32.0f);
            sum += e[i];
        }
        for (int i = 0; i < KS; i++) g[i] = e[i] / sum;
    }
}

__device__ __forceinline__ int reflect224(int i) {
    if (i < 0) return -i;
    if (i > OS - 1) return 2 * (OS - 1) - i;
    return i;
}

__global__ void k_hblur(const float* __restrict__ up,
                        const float* __restrict__ g,
                        float* __restrict__ tmp) {
    int idx = blockIdx.x * 256 + threadIdx.x;
    if (idx >= NB * OS * OS) return;
    int x = idx % OS;
    int row = idx / OS;
    const float* src = up + (size_t)row * OS;
    float acc = 0.f;
#pragma unroll
    for (int t = -GPAD; t <= GPAD; t++) {
        acc += g[t + GPAD] * src[reflect224(x + t)];
    }
    tmp[idx] = acc;
}

__global__ void k_vblur(const float* __restrict__ tmp,
                        const float* __restrict__ g,
                        float* __restrict__ out) {
    int idx = blockIdx.x * 256 + threadIdx.x;
    if (idx >= NB * OS * OS) return;
    int x = idx % OS;
    int y = (idx / OS) % OS;
    int b = idx / (OS * OS);
    const float* src = tmp + (size_t)b * OS * OS;
    float acc = 0.f;
#pragma unroll
    for (int t = -GPAD; t <= GPAD; t++) {
        acc += g[t + GPAD] * src[(size_t)reflect224(y + t) * OS + x];
    }
    out[idx] = acc;
}

// ---------------------------------------------------------------------------
extern "C" void kernel_launch(void* const* d_in, const int* in_sizes, int n_in,
                              void* d_out, int out_size, void* d_ws, size_t ws_size,
                              hipStream_t stream) {
    const float* emb  = (const float*)d_in[0];   // [32,200,56,56]
    const float* mean = (const float*)d_in[1];   // [200,3136]
    const float* icov = (const float*)d_in[2];   // [3136,200,200]
    float* out = (float*)d_out;                  // [32,1,224,224]

    char* ws = (char*)d_ws;
    float* g     = (float*)ws;                            // 33 floats
    float* score = (float*)(ws + 256);                    // 32*3136 floats
    float* tmp   = (float*)(ws + 256 + 401408);           // 32*224*224 floats
    unsigned short* dg = (unsigned short*)(ws + 6824192); // 3136*7168 bf16 (~45MB)

    const int up_blocks = (NB * OS * OS) / 256;           // 6272

    k_gauss_init<<<1, 64, 0, stream>>>(g);
    k_delta<<<784, 256, 0, stream>>>(emb, mean, dg);
    k_mahal2<<<HW, 256, 0, stream>>>(dg, icov, score);
    k_upsample<<<up_blocks, 256, 0, stream>>>(score, out);
    k_hblur<<<up_blocks, 256, 0, stream>>>(out, g, tmp);
    k_vblur<<<up_blocks, 256, 0, stream>>>(tmp, g, out);
}

// Round 3
// 712.001 us; speedup vs baseline: 1.1948x; 1.0114x over previous
//
#include <hip/hip_runtime.h>
#include <math.h>

#define HW   3136
#define NC   200
#define NB   32
#define SS   56
#define OS   224
#define KS   33

typedef __attribute__((ext_vector_type(8))) short          short8;
typedef __attribute__((ext_vector_type(4))) float          f32x4;
typedef __attribute__((ext_vector_type(4))) unsigned short ush4;

__device__ __forceinline__ unsigned short f2bf(float x) {
    unsigned int u = __builtin_bit_cast(unsigned int, x);
    u += 0x7FFFu + ((u >> 16) & 1u);          // RNE (inputs finite)
    return (unsigned short)(u >> 16);
}
__device__ __forceinline__ float bf2f(unsigned short h) {
    unsigned int u = ((unsigned int)h) << 16;
    return __builtin_bit_cast(float, u);
}

// async global->LDS, 16B per lane. LDS dest is wave-uniform base + lane*16.
__device__ __forceinline__ void gload16(const void* g, void* l) {
    __builtin_amdgcn_global_load_lds(
        (const __attribute__((address_space(1))) void*)g,
        (__attribute__((address_space(3))) void*)l, 16, 0, 0);
}

// ---------------------------------------------------------------------------
// K0: coalesced delta transpose. emb[b][c][n]-mean[c][n] -> bf16, laid out
// per pixel as 7 K-chunks [kt][b 0..31][c-in-chunk 0..31] (zero-padded c>=200)
// so k_mahal2 can global_load_lds it linearly and read B-fragments/epilogue
// directly. Grid: 196 n-tiles x 4 b-quarters = 784 blocks.
// ---------------------------------------------------------------------------
__global__ __launch_bounds__(256)
void k_delta(const float* __restrict__ emb,
             const float* __restrict__ mean,
             unsigned short* __restrict__ dg) {
    const int tile = blockIdx.x >> 2;
    const int bq   = blockIdx.x & 3;          // b-quarter: b = bq*8 .. bq*8+7
    const int n0   = tile * 16;
    const int t    = threadIdx.x;

    __shared__ float          mm[32 * 20];    // mean chunk [cl][nl], pad 20
    __shared__ unsigned short tr[256 * 20];   // [b_lo*32+cl][nl], pad 20

    unsigned int* dgU = (unsigned int*)dg;

    for (int kt = 0; kt < 7; kt++) {
        const int c0 = kt * 32;
        // mean chunk: 32 c x 16 n
        if (t < 128) {
            int cl = t >> 2, nl4 = (t & 3) * 4;
            int c = c0 + cl;
            float4 v = {0.f, 0.f, 0.f, 0.f};
            if (c < NC) v = *(const float4*)&mean[(size_t)c * HW + n0 + nl4];
            *(float4*)&mm[cl * 20 + nl4] = v;
        }
        __syncthreads();
        // stage: 256 rows (8 b x 32 cl) x 16 n, 64B-granule coalesced reads
#pragma unroll
        for (int j = 0; j < 4; j++) {
            int row = (t >> 2) + 64 * j;      // 0..255
            int nl4 = (t & 3) * 4;
            int b   = bq * 8 + (row >> 5);
            int cl  = row & 31;
            int c   = c0 + cl;
            ush4 wv = {0, 0, 0, 0};
            if (c < NC) {
                float4 e = *(const float4*)&emb[((size_t)(b * NC + c)) * HW + n0 + nl4];
                float4 m = *(const float4*)&mm[cl * 20 + nl4];
                wv[0] = f2bf(e.x - m.x); wv[1] = f2bf(e.y - m.y);
                wv[2] = f2bf(e.z - m.z); wv[3] = f2bf(e.w - m.w);
            }
            *(ush4*)&tr[row * 20 + nl4] = wv;
        }
        __syncthreads();
        // emit: fully coalesced packed uint writes
#pragma unroll
        for (int j = 0; j < 8; j++) {
            int idx = t + 256 * j;            // 0..2047
            int nl  = idx >> 7, rem = idx & 127;
            int bl  = rem >> 4, cu = rem & 15;
            int cb  = bl * 32 + 2 * cu;
            unsigned int lo = tr[cb * 20 + nl];
            unsigned int hi = tr[(cb + 1) * 20 + nl];
            dgU[((size_t)(n0 + nl) * 7 + kt) * 512 +
                (size_t)(bq * 8 + bl) * 16 + cu] = lo | (hi << 16);
        }
        __syncthreads();
    }
}

// ---------------------------------------------------------------------------
// K1: per-pixel Mahalanobis, symmetric/triangular streaming form.
// M is exactly symmetric, so q = 2*sum_{blockK<blockI} T(I,K) + sum_I T(I,I):
// per row-tile I we stream only k in [0,16(I+1)) (58% of the matrix).
// Block-level factors are per-lane uniform on the A fragment (a lane's 8-wide
// k-range sits entirely in one 16-half): half below diag -> x2 (exact in
// bf16), diag block -> x1, above -> constant-0 fragment (select, no read).
// M rows stream f32 via global_load_lds into a double-buffered padded slab
// (row stride CHp=CH+1 16B-chunks, odd -> conflict-free b128 reads); one
// barrier per tile. Every read region is written by the current tile with
// row/chunk-clamped finite sources, so no LDS-poison NaN can enter the MFMA.
// ---------------------------------------------------------------------------
__global__ __launch_bounds__(256, 4)
void k_mahal2(const unsigned short* __restrict__ dg,
              const float* __restrict__ icov,
              float* __restrict__ score) {
    const int bid = blockIdx.x;
    const int n = (bid & 7) * 392 + (bid >> 3);   // XCD-contiguous pixel index
    const int t = threadIdx.x;

    __shared__ __align__(16) unsigned short dd[7 * 1024]; // bf16 delta [kt][b][c&31]
    __shared__ __align__(16) float slab[2][3200];         // 800 16B-chunks per buf
    __shared__ float qs[NB];

    const float* Mn   = icov + (size_t)n * (NC * NC);
    const char*  dsrc = (const char*)(dg + (size_t)n * 7168);

    // issue delta (896 x16B) + M tile 0 (triangular prefix, 88 chunks), async
    {
        char* lb = (char*)dd;
#pragma unroll
        for (int i = 0; i < 4; i++) {
            int idx = i * 256 + t;
            if (idx < 896)
                gload16(dsrc + (size_t)idx * 16, lb + (i * 256 + (t & 192)) * 16);
        }
        const char* ms = (const char*)Mn;
        char* sb = (char*)&slab[0][0];
        if (t < 88) {                              // nr=16, CH=4, CHp=5, T=88
            int row = t / 5;
            int c   = t - row * 5;
            if (row >= 16) { row = 15; c = 0; }
            if (c >= 4) c = 0;
            gload16(ms + (size_t)row * (NC * 4) + (size_t)c * 16,
                    sb + (t & 192) * 16);
        }
    }
    if (t < NB) qs[t] = 0.f;
    __syncthreads();                              // drains dd + tile0

    const int lane = t & 63;
    const int w    = t >> 6;
    const int col  = lane & 15;
    const int quad = lane >> 4;
    const int bt   = w & 1;                       // b-tile 0/1
    const int kg   = w >> 1;                      // k-group: chunks kg, kg+2, ...
    const int ddb  = (bt * 16 + col) * 32;

    // B fragments (delta rows) live in registers for the whole kernel
    short8 bF[4];
#pragma unroll
    for (int q = 0; q < 4; q++) {
        int kt = kg + 2 * q;
        if (kt < 7)
            bF[q] = *(const short8*)&dd[kt * 1024 + ddb + quad * 8];
    }

    float qacc = 0.f;

#pragma unroll
    for (int it = 0; it < 13; it++) {
        // ---- issue next M tile's triangular prefix (flies across compute,
        //      drained by the end-of-iteration barrier) ----
        if (it < 12) {
            const int tt  = it + 1;
            const int nr  = (tt == 12) ? 8 : 16;
            const int CHn = (4 * (tt + 1) < 50) ? 4 * (tt + 1) : 50;
            const int CHpn = CHn + 1;
            const int T   = nr * CHpn + 8;        // +8 tail pad (clamped srcs)
            const char* ms = (const char*)(Mn + (size_t)tt * 16 * NC);
            char* sb = (char*)&slab[tt & 1][0];
#pragma unroll
            for (int i = 0; i < 4; i++) {
                int idx = i * 256 + t;
                if (idx < T) {
                    int row = idx / CHpn;         // compile-time magic (unrolled)
                    int c   = idx - row * CHpn;
                    if (row >= nr) { row = nr - 1; c = 0; }
                    if (c >= CHn) c = 0;          // stride pad chunk: finite src
                    gload16(ms + (size_t)row * (NC * 4) + (size_t)c * 16,
                            sb + (i * 256 + (t & 192)) * 16);
                }
            }
        }
        // ---- compute tile it ----
        {
            const int CH   = (4 * (it + 1) < 50) ? 4 * (it + 1) : 50;
            const int strd = (CH + 1) * 4;        // floats; odd 16B stride
            const int Cq   = (it + 2) >> 1;       // ceil((it+1)/2) K32-chunks
            const int ig   = 16 * it + col;       // this lane's A-row (M row)
            const float* sl = &slab[it & 1][0];
            f32x4 acc = {0.f, 0.f, 0.f, 0.f};
#pragma unroll
            for (int q = 0; q < 4; q++) {
                const int cq = kg + 2 * q;
                if (cq < Cq) {
                    const int half0 = 32 * cq + (quad >> 1) * 16;
                    float s = 0.f;
                    if (ig < NC) {
                        if (half0 + 16 <= 16 * it) s = 2.f;       // strict lower
                        else if (half0 == 16 * it) s = 1.f;       // diag block
                    }
                    short8 aF = {0, 0, 0, 0, 0, 0, 0, 0};
                    if (s != 0.f) {
                        const f32x4* ap =
                            (const f32x4*)&sl[col * strd + cq * 32 + quad * 8];
                        f32x4 lo = ap[0], hi = ap[1];
                        aF[0] = f2bf(s * lo[0]); aF[1] = f2bf(s * lo[1]);
                        aF[2] = f2bf(s * lo[2]); aF[3] = f2bf(s * lo[3]);
                        aF[4] = f2bf(s * hi[0]); aF[5] = f2bf(s * hi[1]);
                        aF[6] = f2bf(s * hi[2]); aF[7] = f2bf(s * hi[3]);
                    }
                    acc = __builtin_amdgcn_mfma_f32_16x16x32_bf16(aF, bF[q], acc, 0, 0, 0);
                }
            }
            // fold: q-partial = sum_r R[16it+quad*4+r][b] * delta[b][...]
            int off = (it >> 1) * 1024 + ddb + (it & 1) * 16 + quad * 4;
            ush4 dv = *(const ush4*)&dd[off];
            float v = acc[0] * bf2f(dv[0]) + acc[1] * bf2f(dv[1]) +
                      acc[2] * bf2f(dv[2]) + acc[3] * bf2f(dv[3]);
            v += __shfl_xor(v, 16);
            v += __shfl_xor(v, 32);
            qacc += v;
        }
        __syncthreads();
    }

    if (quad == 0) atomicAdd(&qs[bt * 16 + col], qacc);
    __syncthreads();
    if (t < NB) {
        float q = qs[t];
        score[(size_t)t * HW + n] = sqrtf(q > 0.f ? q : 0.f);
    }
}

// ---------------------------------------------------------------------------
// K2: composite post-filter weights. Upsample (U, clamped half-pixel
// bilinear) and gaussian blur (G, reflect pad) are both linear, and the
// same 1-D operator applies to rows and columns:
//   out = (G U) score (G U)^T = W score W^T,   W[y][r] = sum_t g[t] U[refl(y+t)][r]
// W stored padded [224][64] (zeros beyond r=55) + transposed WT[56][224].
// Gaussian normalization matches reference bit-for-bit: e[i]=exp(-x^2/32)/sum.
// ---------------------------------------------------------------------------
__global__ __launch_bounds__(256)
void k_winit(float* __restrict__ W, float* __restrict__ WT) {
    int idx = blockIdx.x * 256 + threadIdx.x;    // 224*64
    if (idx >= 224 * 64) return;
    int y = idx >> 6, r = idx & 63;

    float e[KS]; float sum = 0.f;
#pragma unroll
    for (int i = 0; i < KS; i++) {
        float xx = (float)i - 16.0f;
        e[i] = expf(-(xx * xx) / 32.0f);
        sum += e[i];
    }
    float w = 0.f;
    if (r < 56) {
#pragma unroll
        for (int tt = 0; tt < KS; tt++) {
            int i = y + tt - 16;
            if (i < 0) i = -i;                   // reflect (no edge repeat)
            if (i > OS - 1) i = 2 * (OS - 1) - i;
            float si = 0.25f * (float)i - 0.375f;
            int r0 = (int)floorf(si);
            float f = si - (float)r0;
            int r0c = min(max(r0, 0), SS - 1);
            int r1c = min(max(r0 + 1, 0), SS - 1);
            float u = ((r == r0c) ? (1.f - f) : 0.f) + ((r == r1c) ? f : 0.f);
            w += (e[tt] / sum) * u;
        }
    }
    W[y * 64 + r] = w;
    if (r < 56) WT[r * 224 + y] = w;
}

// ---------------------------------------------------------------------------
// K3: fused upsample+blur: out[b] = W * score[b] * W^T.
// Grid 32 b x 7 row-tiles. Per tile only score rows [rlo,rhi) (<=18) carry
// weight; they're staged zero-padded to 20 rows so every j-loop is a fixed
// fully-unrolled bound (T[20] stays in registers — no scratch). Thread x
// owns T[.]=column x of score-slice * WT (coalesced WT reads, LDS-broadcast
// S reads), then emits 32 output rows against L2-hot W row segments.
// W rows are exactly zero outside [rlo,rhi) for this tile's y-range, so the
// fixed 20-wide dot is exact.
// ---------------------------------------------------------------------------
__global__ __launch_bounds__(256)
void k_post(const float* __restrict__ score,
            const float* __restrict__ W,
            const float* __restrict__ WT,
            float* __restrict__ out) {
    const int b  = blockIdx.x / 7;
    const int yt = blockIdx.x % 7;
    const int y0 = yt * 32;
    const int t  = threadIdx.x;

    const int imin = max(0, y0 - 16);            // reflected taps stay inside
    const int imax = min(OS - 1, y0 + 47);
    const int rlo  = max(0, (int)floorf(0.25f * (float)imin - 0.375f));
    const int rhi  = min(SS, (int)floorf(0.25f * (float)imax - 0.375f) + 2);
    const int NR   = rhi - rlo;                  // <= 18

    __shared__ float S[20 * 60];
    const float* sb = score + (size_t)b * HW;
    for (int idx = t; idx < 20 * 14; idx += 256) {
        int j = idx / 14, c4 = (idx % 14) * 4;
        float4 v = {0.f, 0.f, 0.f, 0.f};
        if (j < NR) v = *(const float4*)&sb[(rlo + j) * SS + c4];
        *(float4*)&S[j * 60 + c4] = v;
    }
    __syncthreads();

    if (t < OS) {
        const int x = t;
        float T[20];
#pragma unroll
        for (int j = 0; j < 20; j++) T[j] = 0.f;
        for (int c = 0; c < SS; c++) {
            float wv = WT[c * OS + x];
#pragma unroll
            for (int j = 0; j < 20; j++) T[j] += S[j * 60 + c] * wv;
        }
        float* ob = out + (size_t)b * (OS * OS);
#pragma unroll 4
        for (int y = y0; y < y0 + 32; y++) {
            const float* wr = W + (size_t)y * 64 + rlo;   // rlo+19 < 64 always
            float acc = 0.f;
#pragma unroll
            for (int j = 0; j < 20; j++) acc += wr[j] * T[j];
            ob[(size_t)y * OS + x] = acc;
        }
    }
}

// ---------------------------------------------------------------------------
extern "C" void kernel_launch(void* const* d_in, const int* in_sizes, int n_in,
                              void* d_out, int out_size, void* d_ws, size_t ws_size,
                              hipStream_t stream) {
    const float* emb  = (const float*)d_in[0];   // [32,200,56,56]
    const float* mean = (const float*)d_in[1];   // [200,3136]
    const float* icov = (const float*)d_in[2];   // [3136,200,200]
    float* out = (float*)d_out;                  // [32,1,224,224]

    char* ws = (char*)d_ws;
    float* score = (float*)(ws + 256);                    // 32*3136 floats
    float* W     = (float*)(ws + 401664);                 // 224*64 floats
    float* WT    = (float*)(ws + 459008);                 // 56*224 floats
    unsigned short* dg = (unsigned short*)(ws + 6824192); // 3136*7168 bf16 (~45MB)

    k_winit<<<56, 256, 0, stream>>>(W, WT);
    k_delta<<<784, 256, 0, stream>>>(emb, mean, dg);
    k_mahal2<<<HW, 256, 0, stream>>>(dg, icov, score);
    k_post<<<NB * 7, 256, 0, stream>>>(score, W, WT, out);
}